// Round 3
// baseline (66.221 us; speedup 1.0000x reference)
//
#include <hip/hip_runtime.h>

// XTermFrequency: per-row vocab frequency = histogram / rowsum.
// Output is >=96% zeros (S=2048 samples into 50257 bins), so:
//   phase 1: dwordx4 zero-fill of the whole row (pure store stream, the same
//            pattern as rocclr fillBuffer which hits 6.4-6.8 TB/s here)
//   phase 2: ~S scattered global fp32 atomicAdds of w*inv (merges duplicates)
// Ordering: __syncthreads() between the phases — hipcc drains vmcnt(0) before
// s_barrier, so the fill stores have completed at L2 (the coherence point
// where the atomics execute, same XCD) before any atomic RMWs those lines.
// No LDS histogram, no chunk loop, two barriers total.
#define VOCAB 50257

__global__ __launch_bounds__(1024) void XTermFrequency_5471788335935_kernel(
    const int* __restrict__ asg, const float* __restrict__ w,
    float* __restrict__ out, int S)
{
    __shared__ float s_sum;

    const int b   = blockIdx.x;
    const int tid = threadIdx.x;
    const long long rowoff = (long long)b * S;
    const int*   __restrict__ row  = asg + rowoff;
    const float* __restrict__ wrow = w   + rowoff;
    float*       __restrict__ orow = out + (long long)b * VOCAB;

    // Register-cache this thread's samples when S == 2*blockDim (bench shape:
    // S=2048, block=1024). Generic fallback re-reads global in the atomic phase.
    const bool cached = ((S & 1) == 0) && ((S >> 1) == (int)blockDim.x);
    int2   ra = make_int2(0, 0);
    float2 rw = make_float2(0.f, 0.f);
    float  ws = 0.f;
    if (cached) {
        ra = reinterpret_cast<const int2*>(row)[tid];
        rw = reinterpret_cast<const float2*>(wrow)[tid];
        ws = rw.x + rw.y;
    } else {
        for (int s = tid; s < S; s += blockDim.x) ws += wrow[s];
    }

    if (tid == 0) s_sum = 0.f;
    __syncthreads();
    // wave(64) shuffle reduce, one LDS atomic per wave
    #pragma unroll
    for (int off = 32; off > 0; off >>= 1) ws += __shfl_down(ws, off, 64);
    if ((tid & 63) == 0) atomicAdd(&s_sum, ws);

    // --- phase 1: zero-fill the row ---
    // orow is only 4B-aligned (VOCAB odd); scalar head to reach 16B alignment,
    // dwordx4 main body, scalar tail.
    const int head = (int)(((16u - ((unsigned)(uintptr_t)orow & 15u)) & 15u) >> 2);
    if (tid < head) orow[tid] = 0.f;
    const int nvec = (VOCAB - head) >> 2;
    float4* __restrict__ vb = reinterpret_cast<float4*>(orow + head);
    const float4 z4 = make_float4(0.f, 0.f, 0.f, 0.f);
    for (int i = tid; i < nvec; i += (int)blockDim.x) vb[i] = z4;
    const int tpos = head + (nvec << 2) + tid;
    if (tid < 4 && tpos < VOCAB) orow[tpos] = 0.f;

    // drain fill stores to L2 + publish s_sum
    __syncthreads();

    // --- phase 2: scatter-add the samples ---
    // s_sum = 2048.0 for the bench -> inv = 2^-11 exact; count*inv exact fp32.
    const float inv = 1.0f / s_sum;
    if (cached) {
        atomicAdd(&orow[ra.x], rw.x * inv);
        atomicAdd(&orow[ra.y], rw.y * inv);
    } else {
        for (int s = tid; s < S; s += blockDim.x)
            atomicAdd(&orow[row[s]], wrow[s] * inv);
    }
}

extern "C" void kernel_launch(void* const* d_in, const int* in_sizes, int n_in,
                              void* d_out, int out_size, void* d_ws, size_t ws_size,
                              hipStream_t stream) {
    const int*   asg = (const int*)d_in[0];
    const float* w   = (const float*)d_in[1];
    float*       out = (float*)d_out;

    const int B = out_size / VOCAB;          // 512
    const int S = in_sizes[0] / B;           // 2048

    XTermFrequency_5471788335935_kernel<<<B, 1024, 0, stream>>>(asg, w, out, S);
}

// Round 4
// 65.722 us; speedup vs baseline: 1.0076x; 1.0076x over previous
//
#include <hip/hip_runtime.h>

// XTermFrequency: per-row vocab frequency = histogram / rowsum.
// Output is >=96% zeros (S=2048 samples into 50257 bins), so:
//   phase 1: dwordx4 zero-fill of the whole row (pure store stream, the same
//            pattern as rocclr fillBuffer which hits 6.1-6.8 TB/s here)
//   phase 2: ~S scattered NATIVE fp32 atomicAdds of w*inv (merges duplicates)
// R3 lesson: plain atomicAdd(float*) compiles to a CAS retry loop (no
// -munsafe-fp-atomics) -> 2 TB/s. unsafeAtomicAdd emits global_atomic_add_f32
// (native, fire-and-forget). Safe: coarse-grained device HBM, and each output
// line is touched only by its own block; fill stores are drained (vmcnt(0)
// inside __syncthreads) before the RMWs hit the same lines.
#define VOCAB 50257

__global__ __launch_bounds__(1024) void XTermFrequency_5471788335935_kernel(
    const int* __restrict__ asg, const float* __restrict__ w,
    float* __restrict__ out, int S)
{
    __shared__ float s_sum;

    const int b   = blockIdx.x;
    const int tid = threadIdx.x;
    const long long rowoff = (long long)b * S;
    const int*   __restrict__ row  = asg + rowoff;
    const float* __restrict__ wrow = w   + rowoff;
    float*       __restrict__ orow = out + (long long)b * VOCAB;

    // Register-cache this thread's samples when S == 2*blockDim (bench shape:
    // S=2048, block=1024). Generic fallback re-reads global in the atomic phase.
    const bool cached = ((S & 1) == 0) && ((S >> 1) == (int)blockDim.x);
    int2   ra = make_int2(0, 0);
    float2 rw = make_float2(0.f, 0.f);
    float  ws = 0.f;
    if (cached) {
        ra = reinterpret_cast<const int2*>(row)[tid];
        rw = reinterpret_cast<const float2*>(wrow)[tid];
        ws = rw.x + rw.y;
    } else {
        for (int s = tid; s < S; s += blockDim.x) ws += wrow[s];
    }

    if (tid == 0) s_sum = 0.f;
    __syncthreads();
    // wave(64) shuffle reduce, one (native ds_add) LDS atomic per wave
    #pragma unroll
    for (int off = 32; off > 0; off >>= 1) ws += __shfl_down(ws, off, 64);
    if ((tid & 63) == 0) atomicAdd(&s_sum, ws);

    // --- phase 1: zero-fill the row ---
    // orow is only 4B-aligned (VOCAB odd); scalar head to reach 16B alignment,
    // dwordx4 main body, scalar tail.
    const int head = (int)(((16u - ((unsigned)(uintptr_t)orow & 15u)) & 15u) >> 2);
    if (tid < head) orow[tid] = 0.f;
    const int nvec = (VOCAB - head) >> 2;
    float4* __restrict__ vb = reinterpret_cast<float4*>(orow + head);
    const float4 z4 = make_float4(0.f, 0.f, 0.f, 0.f);
    for (int i = tid; i < nvec; i += (int)blockDim.x) vb[i] = z4;
    const int tpos = head + (nvec << 2) + tid;
    if (tid < 4 && tpos < VOCAB) orow[tpos] = 0.f;

    // drain fill stores + publish s_sum
    __syncthreads();

    // --- phase 2: scatter-add the samples (native fp32 fadd) ---
    // s_sum = 2048.0 for the bench -> inv = 2^-11 exact; count*inv exact fp32.
    const float inv = 1.0f / s_sum;
    if (cached) {
        unsafeAtomicAdd(&orow[ra.x], rw.x * inv);
        unsafeAtomicAdd(&orow[ra.y], rw.y * inv);
    } else {
        for (int s = tid; s < S; s += blockDim.x)
            unsafeAtomicAdd(&orow[row[s]], wrow[s] * inv);
    }
}

extern "C" void kernel_launch(void* const* d_in, const int* in_sizes, int n_in,
                              void* d_out, int out_size, void* d_ws, size_t ws_size,
                              hipStream_t stream) {
    const int*   asg = (const int*)d_in[0];
    const float* w   = (const float*)d_in[1];
    float*       out = (float*)d_out;

    const int B = out_size / VOCAB;          // 512
    const int S = in_sizes[0] / B;           // 2048

    XTermFrequency_5471788335935_kernel<<<B, 1024, 0, stream>>>(asg, w, out, S);
}

// Round 5
// 27.733 us; speedup vs baseline: 2.3878x; 2.3698x over previous
//
#include <hip/hip_runtime.h>

// XTermFrequency: per-row vocab frequency = histogram / rowsum.
// R4 lesson: global scattered atomics on the 103MB output are L2-miss
// latency-bound (~66us regardless of CAS vs native fadd). Back to the LDS
// histogram + pure streaming stores (R2, 23.8us), improved:
//  - weights are 1.0 (verified at runtime via ballot): counts fit u16
//    (max = S = 2048), so pack 2 bins/u32 -> chunk LDS halves -> 2 chunks
//    instead of 4: half the barriers, half the sample re-scans.
//  - fp32 4-chunk fallback (same LDS buffer) keeps general-weight correctness.
// Barriers in the chunk loops wait lgkmcnt only (LDS ordering); global stores
// stay in flight across chunks.
#define VOCAB  50257
#define CHUNKB 25132              // bins per packed chunk (even)
#define NPACK0 12566              // u32 words, chunk 0 (50264 B LDS)
#define NPACK1 12563              // u32 words, chunk 1 (last word: bin 50257 invalid)
#define NCHUNKF 4
#define CHUNKF  12566             // fp32 fallback: 4*12566 >= VOCAB, same buffer

#define LDS_BARRIER()                                            \
    do {                                                         \
        asm volatile("s_waitcnt lgkmcnt(0)" ::: "memory");       \
        __builtin_amdgcn_s_barrier();                            \
        __builtin_amdgcn_sched_barrier(0);                       \
    } while (0)

__global__ __launch_bounds__(1024) void XTermFrequency_5471788335935_kernel(
    const int* __restrict__ asg, const float* __restrict__ w,
    float* __restrict__ out, int S)
{
    __shared__ uint32_t h32[NPACK0];   // 50264 B -> 2 blocks/CU
    __shared__ float s_sum;
    __shared__ int   s_ones;

    const int b   = blockIdx.x;
    const int tid = threadIdx.x;
    const long long rowoff = (long long)b * S;
    const int*   __restrict__ row  = asg + rowoff;
    const float* __restrict__ wrow = w   + rowoff;
    float*       __restrict__ orow = out + (long long)b * VOCAB;

    // Register-cache this thread's samples when S == 2*blockDim (bench shape).
    const bool cached = ((S & 1) == 0) && ((S >> 1) == (int)blockDim.x);
    int2   ra = make_int2(0, 0);
    float2 rw = make_float2(0.f, 0.f);
    float  ws = 0.f;
    bool   myones = false;
    if (cached) {
        ra = reinterpret_cast<const int2*>(row)[tid];
        rw = reinterpret_cast<const float2*>(wrow)[tid];
        ws = rw.x + rw.y;
        myones = (rw.x == 1.0f) && (rw.y == 1.0f);
    } else {
        for (int s = tid; s < S; s += blockDim.x) ws += wrow[s];
    }

    if (tid == 0) { s_sum = 0.f; s_ones = cached ? 1 : 0; }
    __syncthreads();
    // wave(64) shuffle reduce + all-ones vote; one LDS atomic per wave
    #pragma unroll
    for (int off = 32; off > 0; off >>= 1) ws += __shfl_down(ws, off, 64);
    const unsigned long long bal = __ballot(myones);
    if ((tid & 63) == 0) {
        atomicAdd(&s_sum, ws);
        if (bal != ~0ull) atomicAnd(&s_ones, 0);
    }
    __syncthreads();

    const float inv = 1.0f / s_sum;   // 2^-11 exact for the bench

    if (s_ones) {
        // ---- packed u16 counting path (2 chunks) ----
        for (int j = tid; j < NPACK0; j += 1024) h32[j] = 0u;
        LDS_BARRIER();
        const int phase = b & 1;      // stagger store bursts across blocks
        #pragma unroll
        for (int cc = 0; cc < 2; ++cc) {
            const int c  = cc ^ phase;
            const int lo = c * CHUNKB;
            const int np = c ? NPACK1 : NPACK0;
            const int v0 = ra.x - lo, v1 = ra.y - lo;
            if ((unsigned)v0 < (unsigned)CHUNKB)
                atomicAdd(&h32[v0 >> 1], 1u << ((v0 & 1) << 4));
            if ((unsigned)v1 < (unsigned)CHUNKB)
                atomicAdd(&h32[v1 >> 1], 1u << ((v1 & 1) << 4));
            LDS_BARRIER();
            for (int j = tid; j < np; j += 1024) {
                const uint32_t wd = h32[j];
                h32[j] = 0u;                      // re-zero for next chunk
                const int i0 = lo + (j << 1);
                orow[i0] = (float)(wd & 0xffffu) * inv;
                if (i0 + 1 < VOCAB)
                    orow[i0 + 1] = (float)(wd >> 16) * inv;
            }
            LDS_BARRIER();
        }
    } else {
        // ---- general fp32-weight path (4 chunks, R2 structure) ----
        float* hf = reinterpret_cast<float*>(h32);
        for (int i = tid; i < CHUNKF; i += blockDim.x) hf[i] = 0.f;
        LDS_BARRIER();
        for (int c = 0; c < NCHUNKF; ++c) {
            const int lo = c * CHUNKF;
            if (cached) {
                const int v0 = ra.x - lo, v1 = ra.y - lo;
                if ((unsigned)v0 < (unsigned)CHUNKF) atomicAdd(&hf[v0], rw.x);
                if ((unsigned)v1 < (unsigned)CHUNKF) atomicAdd(&hf[v1], rw.y);
            } else {
                for (int s = tid; s < S; s += blockDim.x) {
                    const int v = row[s] - lo;
                    if ((unsigned)v < (unsigned)CHUNKF) atomicAdd(&hf[v], wrow[s]);
                }
            }
            LDS_BARRIER();
            const int hi = min(CHUNKF, VOCAB - lo);
            for (int i = tid; i < hi; i += blockDim.x) {
                const float h = hf[i];
                hf[i] = 0.f;
                orow[lo + i] = h * inv;
            }
            LDS_BARRIER();
        }
    }
}

extern "C" void kernel_launch(void* const* d_in, const int* in_sizes, int n_in,
                              void* d_out, int out_size, void* d_ws, size_t ws_size,
                              hipStream_t stream) {
    const int*   asg = (const int*)d_in[0];
    const float* w   = (const float*)d_in[1];
    float*       out = (float*)d_out;

    const int B = out_size / VOCAB;          // 512
    const int S = in_sizes[0] / B;           // 2048

    XTermFrequency_5471788335935_kernel<<<B, 1024, 0, stream>>>(asg, w, out, S);
}

// Round 6
// 23.979 us; speedup vs baseline: 2.7617x; 1.1566x over previous
//
#include <hip/hip_runtime.h>

// XTermFrequency: per-row vocab frequency = histogram / rowsum.
// Structure (R2, best so far at 23.8us): one block per row, fp32 LDS histogram
// in 4 vocab chunks (50KB LDS -> 2 blocks/CU), samples register-cached,
// lgkmcnt-only barriers so global stores stay in flight across chunks.
// R6 change: the store loop was ~8us of serialized scalar LDS time
// (ds_read_b32 + ds_write_b32 per bin). Vectorize: ds_read_b128 + b128
// re-zero + global_store_dwordx4 (inline asm -- multi-dword global stores
// need only 4B alignment on CDNA, which odd rows have; compiler won't emit
// x4 on its own without 16B alignment proof).
#define VOCAB  50257
#define NCHUNK 4
#define CHUNK  12565                 // 4*12565 = 50260 >= VOCAB
#define NVEC4  3142                  // padded f32x4 words (12568 floats)

typedef float f32x4 __attribute__((ext_vector_type(4)));

// Barrier ordering LDS only; global stores remain in flight.
#define LDS_BARRIER()                                            \
    do {                                                         \
        asm volatile("s_waitcnt lgkmcnt(0)" ::: "memory");       \
        __builtin_amdgcn_s_barrier();                            \
        __builtin_amdgcn_sched_barrier(0);                       \
    } while (0)

__global__ __launch_bounds__(1024) void XTermFrequency_5471788335935_kernel(
    const int* __restrict__ asg, const float* __restrict__ w,
    float* __restrict__ out, int S)
{
    __shared__ f32x4 hist4[NVEC4];           // 50272 B
    __shared__ float s_sum;
    float* hist = reinterpret_cast<float*>(hist4);

    const int b   = blockIdx.x;
    const int tid = threadIdx.x;
    const long long rowoff = (long long)b * S;
    const int*   __restrict__ row  = asg + rowoff;
    const float* __restrict__ wrow = w   + rowoff;
    float*       __restrict__ orow = out + (long long)b * VOCAB;

    // Register-cache this thread's samples when S == 2*blockDim (bench shape:
    // S=2048, block=1024). Generic fallback re-reads global in scatter phase.
    const bool cached = ((S & 1) == 0) && ((S >> 1) == (int)blockDim.x);
    int2   ra = make_int2(0, 0);
    float2 rw = make_float2(0.f, 0.f);
    float  ws = 0.f;
    if (cached) {
        ra = reinterpret_cast<const int2*>(row)[tid];
        rw = reinterpret_cast<const float2*>(wrow)[tid];
        ws = rw.x + rw.y;
    } else {
        for (int s = tid; s < S; s += blockDim.x) ws += wrow[s];
    }

    if (tid == 0) s_sum = 0.f;
    __syncthreads();
    // wave(64) shuffle reduce, one native ds-atomic per wave
    #pragma unroll
    for (int off = 32; off > 0; off >>= 1) ws += __shfl_down(ws, off, 64);
    if ((tid & 63) == 0) atomicAdd(&s_sum, ws);

    // Zero the (padded) histogram once; store loop re-zeros as it drains.
    const f32x4 z4 = {0.f, 0.f, 0.f, 0.f};
    for (int j = tid; j < NVEC4; j += 1024) hist4[j] = z4;
    LDS_BARRIER();   // zeros + s_sum visible

    const float inv = 1.0f / s_sum;   // 2^-11 exact for the bench shape

    // Stagger chunk order across blocks to spread HBM store bursts.
    const int phase = b & (NCHUNK - 1);

    for (int cc = 0; cc < NCHUNK; ++cc) {
        const int c  = (cc + phase) & (NCHUNK - 1);
        const int lo = c * CHUNK;

        // ---- scatter into LDS histogram (native ds fadd) ----
        if (cached) {
            const int v0 = ra.x - lo;
            const int v1 = ra.y - lo;
            if ((unsigned)v0 < (unsigned)CHUNK) atomicAdd(&hist[v0], rw.x);
            if ((unsigned)v1 < (unsigned)CHUNK) atomicAdd(&hist[v1], rw.y);
        } else {
            for (int s = tid; s < S; s += blockDim.x) {
                const int v = row[s] - lo;
                if ((unsigned)v < (unsigned)CHUNK) atomicAdd(&hist[v], wrow[s]);
            }
        }
        LDS_BARRIER();

        // ---- drain chunk: b128 read, b128 re-zero, dwordx4 store ----
        const int hi = min(CHUNK, VOCAB - lo);   // 12565 / 12562
        const int nv = hi >> 2;                  // exact f32x4 count
        for (int j = tid; j < nv; j += 1024) {
            f32x4 h = hist4[j];                  // ds_read_b128 (16B-aligned LDS)
            hist4[j] = z4;                       // ds_write_b128 re-zero
            f32x4 r = h * inv;
            float* p = orow + lo + (j << 2);     // 4B-aligned is enough for x4
            asm volatile("global_store_dwordx4 %0, %1, off"
                         :: "v"(p), "v"(r));
        }
        for (int i = (nv << 2) + tid; i < hi; i += 1024) {  // 1-2 element tail
            const float h = hist[i];
            hist[i] = 0.f;
            orow[lo + i] = h * inv;
        }
        LDS_BARRIER();   // zeros visible before next chunk's scatter
    }
}

extern "C" void kernel_launch(void* const* d_in, const int* in_sizes, int n_in,
                              void* d_out, int out_size, void* d_ws, size_t ws_size,
                              hipStream_t stream) {
    const int*   asg = (const int*)d_in[0];
    const float* w   = (const float*)d_in[1];
    float*       out = (float*)d_out;

    const int B = out_size / VOCAB;          // 512
    const int S = in_sizes[0] / B;           // 2048

    XTermFrequency_5471788335935_kernel<<<B, 1024, 0, stream>>>(asg, w, out, S);
}